// Round 20
// baseline (104.643 us; speedup 1.0000x reference)
//
#include <hip/hip_runtime.h>
#include <hip/hip_bf16.h>
#include <math.h>

#define NH 12
#define SEQ 1024
#define HD 64
#define HDIM 768
#define BSZ 4
#define RK 129
#define FMIN -3.4028234663852886e38f
#define LOG2E 1.4426950408889634f

typedef __attribute__((ext_vector_type(8))) short short8;
typedef __attribute__((ext_vector_type(4))) short short4v;
typedef __attribute__((ext_vector_type(2))) unsigned uint2v;
typedef __attribute__((ext_vector_type(8))) _Float16 f16x8;
typedef __attribute__((ext_vector_type(4))) float f32x4;

__device__ inline short f2bf(float x) {
    union { __hip_bfloat16 h; short s; } u;
    u.h = __float2bfloat16(x);
    return u.s;
}
__device__ inline unsigned cvtpk(float lo, float hi) {
    unsigned r;
    asm("v_cvt_pk_bf16_f32 %0, %1, %2" : "=v"(r) : "v"(lo), "v"(hi));
    return r;
}
__device__ inline float fexp2(float x) {
    float r;
    asm("v_exp_f32 %0, %1" : "=v"(r) : "v"(x));
    return r;
}

__device__ inline void async_load16(void* lds, const void* g) {
    __builtin_amdgcn_global_load_lds(
        (const __attribute__((address_space(1))) unsigned int*)g,
        (__attribute__((address_space(3))) unsigned int*)lds, 16, 0, 0);
}

#define BAR()      asm volatile("s_barrier" ::: "memory")
#define WAITV0()   asm volatile("s_waitcnt vmcnt(0)" ::: "memory")
#define WAITLGKM() do { asm volatile("s_waitcnt lgkmcnt(0)" ::: "memory"); \
                        __builtin_amdgcn_sched_barrier(0); } while (0)

// ---------------- Kernel 0: prep = f16 convert (X, Ek) + Evt + W transpose --
#define NXCHUNK 393216   // 4096*768/8
#define NECHUNK 1032     // 129*64/8
#define NEVCHUNK 1280    // 64*160/8
#define NCONVB ((NXCHUNK + NECHUNK + NEVCHUNK + 255) / 256)   // 1548
#define NTRB   (144 * 3)                                      // 432
__global__ __launch_bounds__(256) void prep_kernel(
    const float* __restrict__ X, const float* __restrict__ Ek,
    const float* __restrict__ Ev,
    const float* __restrict__ Wq, const float* __restrict__ Wk, const float* __restrict__ Wv,
    _Float16* __restrict__ Xh, _Float16* __restrict__ Ekh, short* __restrict__ Evt,
    _Float16* __restrict__ Wtq, _Float16* __restrict__ Wtk, _Float16* __restrict__ Wtv)
{
    const int bidg = blockIdx.x;
    if (bidg < NCONVB) {
        int idx = bidg * 256 + threadIdx.x;
        if (idx < NXCHUNK + NECHUNK) {
            const float* src;
            _Float16* dst;
            if (idx < NXCHUNK) { src = X; dst = Xh; }
            else { idx -= NXCHUNK; src = Ek; dst = Ekh; }
            float4 a = ((const float4*)src)[idx * 2];
            float4 b = ((const float4*)src)[idx * 2 + 1];
            f16x8 o;
            o[0] = (_Float16)a.x; o[1] = (_Float16)a.y; o[2] = (_Float16)a.z; o[3] = (_Float16)a.w;
            o[4] = (_Float16)b.x; o[5] = (_Float16)b.y; o[6] = (_Float16)b.z; o[7] = (_Float16)b.w;
            ((f16x8*)dst)[idx] = o;
        } else if (idx < NXCHUNK + NECHUNK + NEVCHUNK) {
            idx -= NXCHUNK + NECHUNK;
            const int dim = idx / 20;
            const int r0  = (idx % 20) * 8;
            short8 o;
#pragma unroll
            for (int e = 0; e < 8; ++e) {
                int rel = r0 + e;
                float v = (rel < RK) ? Ev[(size_t)rel * HD + dim] : 0.0f;
                o[e] = f2bf(v);
            }
            *(short8*)&Evt[(size_t)dim * 160 + r0] = o;
        }
        return;
    }
    const int bid2 = bidg - NCONVB;
    const int z = bid2 / 144;
    const int r = bid2 % 144;
    const float* __restrict__ W = (z == 0) ? Wq : (z == 1) ? Wk : Wv;
    _Float16* __restrict__ Wt   = (z == 0) ? Wtq : (z == 1) ? Wtk : Wtv;

    __shared__ float sT[64][65];
    const int t  = threadIdx.x;
    const int k0 = (r / 12) * 64;
    const int n0 = (r % 12) * 64;

    const int c  = (t & 15) * 4;
    const int kr = t >> 4;
#pragma unroll
    for (int rr = 0; rr < 4; ++rr) {
        float4 v = *(const float4*)&W[(size_t)(k0 + kr + rr * 16) * HDIM + n0 + c];
        sT[c + 0][kr + rr * 16] = v.x;
        sT[c + 1][kr + rr * 16] = v.y;
        sT[c + 2][kr + rr * 16] = v.z;
        sT[c + 3][kr + rr * 16] = v.w;
    }
    __syncthreads();
    const int rn = t >> 2;
    const int ck = (t & 3) * 16;
#pragma unroll
    for (int g = 0; g < 2; ++g) {
        f16x8 o;
#pragma unroll
        for (int e = 0; e < 8; ++e) o[e] = (_Float16)sT[rn][ck + g * 8 + e];
        *(f16x8*)&Wt[(size_t)(n0 + rn) * HDIM + k0 + ck + g * 8] = o;
    }
}

// ---------------- Kernel 1: QKV projection via f16 MFMA (R8 shape) ---------
// Q is scaled by log2(e) at store so attn can use exp2 directly.
__global__ __launch_bounds__(256) void qkv_mfma_kernel(
    const _Float16* __restrict__ Xh,
    const _Float16* __restrict__ Wtq, const _Float16* __restrict__ Wtk, const _Float16* __restrict__ Wtv,
    const float* __restrict__ bq, const float* __restrict__ bk, const float* __restrict__ bv,
    _Float16* __restrict__ Qo, _Float16* __restrict__ Ko, short* __restrict__ Vt)
{
    int bid = blockIdx.x;
    bid = (bid & 7) * 72 + (bid >> 3);          // XCD swizzle (576 = 8*72)
    const int which = bid / 192;
    const int rem   = bid % 192;
    const int n0    = (rem / 32) * 128;
    const int m0    = (rem % 32) * 128;
    const _Float16* __restrict__ Wt = (which == 0) ? Wtq : (which == 1) ? Wtk : Wtv;
    const float* __restrict__ bias  = (which == 0) ? bq : (which == 1) ? bk : bv;
    const float qscale = (which == 0) ? LOG2E : 1.0f;

    __shared__ __align__(16) _Float16 sA[128 * 64];
    __shared__ __align__(16) _Float16 sB[128 * 64];

    const int t  = threadIdx.x;
    const int w  = t >> 6, l = t & 63;
    const int lq = l & 15, lg = l >> 4;
    const int wr = w >> 1, wc = w & 1;

    f32x4 acc[4][4];
#pragma unroll
    for (int i = 0; i < 4; ++i)
#pragma unroll
        for (int j = 0; j < 4; ++j) acc[i][j] = (f32x4){0.f, 0.f, 0.f, 0.f};

    for (int k0 = 0; k0 < HDIM; k0 += 64) {
        __syncthreads();
#pragma unroll
        for (int r = 0; r < 4; ++r) {
            const int cib = r * 256 + w * 64;
            const int ci  = cib + l;
            const int row = ci >> 3, cr = ci & 7;
            const int lc  = cr ^ (row & 7);
            async_load16(&sA[(size_t)cib * 8],
                         &Xh[(size_t)(m0 + row) * HDIM + k0 + lc * 8]);
            async_load16(&sB[(size_t)cib * 8],
                         &Wt[(size_t)(n0 + row) * HDIM + k0 + lc * 8]);
        }
        __syncthreads();

        f16x8 af[4][2], bf[4][2];
#pragma unroll
        for (int i = 0; i < 4; ++i) {
#pragma unroll
            for (int ks = 0; ks < 2; ++ks) {
                int ra = wr * 64 + i * 16 + lq;
                af[i][ks] = *(const f16x8*)((const char*)sA +
                            ra * 128 + ((ks * 64 + lg * 16) ^ ((ra & 7) << 4)));
                int rb = wc * 64 + i * 16 + lq;
                bf[i][ks] = *(const f16x8*)((const char*)sB +
                            rb * 128 + ((ks * 64 + lg * 16) ^ ((rb & 7) << 4)));
            }
        }
#pragma unroll
        for (int i = 0; i < 4; ++i)
#pragma unroll
            for (int j = 0; j < 4; ++j) {
                acc[i][j] = __builtin_amdgcn_mfma_f32_16x16x32_f16(af[i][0], bf[j][0], acc[i][j], 0, 0, 0);
                acc[i][j] = __builtin_amdgcn_mfma_f32_16x16x32_f16(af[i][1], bf[j][1], acc[i][j], 0, 0, 0);
            }
    }

    _Float16* __restrict__ Yh = (which == 0) ? Qo : Ko;
#pragma unroll
    for (int i = 0; i < 4; ++i) {
        const int mb = m0 + wr * 64 + i * 16 + lg * 4;
        const int bb = mb >> 10, ss = mb & 1023;
#pragma unroll
        for (int j = 0; j < 4; ++j) {
            const int n  = n0 + wc * 64 + j * 16 + lq;
            const float bv4 = bias[n];
            const int hh = n >> 6, dd = n & 63;
            if (which == 2) {
                short4v pk;
#pragma unroll
                for (int reg = 0; reg < 4; ++reg)
                    pk[reg] = f2bf(acc[i][j][reg] + bv4);
                *(short4v*)&Vt[((size_t)(bb * NH + hh) * HD + dd) * SEQ + ss] = pk;
            } else {
#pragma unroll
                for (int reg = 0; reg < 4; ++reg) {
                    const size_t off = ((size_t)(bb * NH + hh) * SEQ + ss + reg) * HD + dd;
                    Yh[off] = (_Float16)((acc[i][j][reg] + bv4) * qscale);
                }
            }
        }
    }
}

// ---------------- Kernel 2: ring attention, V direct-to-registers ----------
// R19 minus the V LDS path: PV B-fragments are 16B contiguous per-lane global
// loads from Vt, prefetched depth-1 into named regs; iter-bottom vmcnt(0)
// (asm, memory clobber - cannot be sunk) drains them with the K DMAs.
// LDS 25.6 KB.
__global__ __launch_bounds__(256, 3) void attn_mfma_kernel(
    const _Float16* __restrict__ Q, const _Float16* __restrict__ K,
    const short* __restrict__ Vt, const float* __restrict__ mask,
    const _Float16* __restrict__ Ekh, const short* __restrict__ Evt,
    float* __restrict__ out)
{
    __shared__ __align__(16) char smem[25600];
    // [0)      K ring  4 x [32][64] f16  (16384 B)
    // [16384)  sPscr   4 waves x [16][40] bf16 (5120 B, 80B stride)
    // [21504)  sMt     [1024] f32        (4096 B)
    // Prologue overlay: P_pos table, 4 waves x [16][132] f16 at w*4224 (16896 B)
    // Epilogue overlay: bandLds, 4 waves x [16][160] bf16 at w*5120 (20480 B)
    float* sMt = (float*)(smem + 21504);

    int bid = blockIdx.x;
    bid = (bid & 7) * 96 + (bid >> 3);   // XCD chunk: 768 = 8*96
    const int bh = bid >> 4;
    const int i0 = (bid & 15) * 64;
    const int b  = bh / NH;
    const int h  = bh - b * NH;

    const int t  = threadIdx.x;
    const int w  = t >> 6;
    const int l  = t & 63;
    const int lq = l & 15;
    const int lg = l >> 4;
    const int wrow0 = i0 + w * 16;
    const int bt0 = __builtin_amdgcn_readfirstlane(((wrow0 - 64 + 1024) >> 5) - 32);

    const int krow = t >> 3, klc = (t & 7) ^ (krow & 7);
    const _Float16* Ksrc = K + ((size_t)bh * SEQ + krow) * HD + klc * 8;
    // per-lane V fragment base: row (d) = nt*16+lq, col (s) = jtc*32 + lg*8
    const short* Vg = Vt + ((size_t)bh * HD + lq) * SEQ + lg * 8;

    const _Float16* qp = Q + ((size_t)bh * SEQ + wrow0 + lq) * HD;
    f16x8 qf0 = *(const f16x8*)&qp[lg * 8];
    f16x8 qf1 = *(const f16x8*)&qp[32 + lg * 8];

    // ---- prologue: P_pos -> overlay LDS -> 40 regs per lane ----
    _Float16* povl = (_Float16*)(smem + w * 4224);   // [16][132] f16
#pragma unroll
    for (int nt = 0; nt < 9; ++nt) {
        int cc = nt * 16 + lq;
        f16x8 eb0 = {0, 0, 0, 0, 0, 0, 0, 0};
        f16x8 eb1 = {0, 0, 0, 0, 0, 0, 0, 0};
        if (cc < RK) {
            eb0 = *(const f16x8*)&Ekh[(size_t)cc * HD + lg * 8];
            eb1 = *(const f16x8*)&Ekh[(size_t)cc * HD + 32 + lg * 8];
        }
        f32x4 pc = {0.f, 0.f, 0.f, 0.f};
        pc = __builtin_amdgcn_mfma_f32_16x16x32_f16(qf0, eb0, pc, 0, 0, 0);
        pc = __builtin_amdgcn_mfma_f32_16x16x32_f16(qf1, eb1, pc, 0, 0, 0);
        if (cc < RK) {
#pragma unroll
            for (int reg = 0; reg < 4; ++reg)
                povl[(lg * 4 + reg) * 132 + cc] = (_Float16)pc[reg];
        }
    }
    float ppos[5][2][4];
#pragma unroll
    for (int s = 0; s < 5; ++s) {
        const int jts = bt0 + s;
#pragma unroll
        for (int ct = 0; ct < 2; ++ct)
#pragma unroll
            for (int reg = 0; reg < 4; ++reg) {
                const int rel = jts * 32 + ct * 16 + lg * 4 + reg - wrow0 - lq + 64;
                float v = 0.f;
                if ((unsigned)jts < 32u && (unsigned)rel < (unsigned)RK)
                    v = (float)povl[lq * 132 + rel];
                ppos[s][ct][reg] = v;
            }
    }

    // mask -> LDS f32 exp2-domain terms
    {
        float4 mv = *(const float4*)&mask[(size_t)b * SEQ + t * 4];
        float4 mo;
        mo.x = ((1.0f - mv.x) * FMIN) * LOG2E;
        mo.y = ((1.0f - mv.y) * FMIN) * LOG2E;
        mo.z = ((1.0f - mv.z) * FMIN) * LOG2E;
        mo.w = ((1.0f - mv.w) * FMIN) * LOG2E;
        *(float4*)&sMt[t * 4] = mo;
    }

    WAITLGKM();   // ppos gathers complete before K DMA overwrites the overlay
    BAR();

    // stage K subtiles 0,1 + V fragments 0,1 into registers
    async_load16(smem + t * 16,         Ksrc);
    async_load16(smem + 4096 + t * 16,  Ksrc + 32 * HD);
    short8 vA[4], vB[4], nA[4], nB[4];
#pragma unroll
    for (int nt = 0; nt < 4; ++nt) {
        vA[nt] = *(const short8*)(Vg + (size_t)nt * 16 * SEQ);
        vB[nt] = *(const short8*)(Vg + (size_t)nt * 16 * SEQ + 32);
    }
    WAITV0();
    BAR();

    f32x4 acc[4];
#pragma unroll
    for (int nt = 0; nt < 4; ++nt) acc[nt] = (f32x4){0.f, 0.f, 0.f, 0.f};
    f32x4 zacc = {0.f, 0.f, 0.f, 0.f};

    const short8 ones = {0x3F80, 0x3F80, 0x3F80, 0x3F80,
                         0x3F80, 0x3F80, 0x3F80, 0x3F80};

    unsigned band[5][2][2];
#pragma unroll
    for (int s = 0; s < 5; ++s)
#pragma unroll
        for (int ct = 0; ct < 2; ++ct) { band[s][ct][0] = 0u; band[s][ct][1] = 0u; }

    const int ck0 = ((lg ^ (lq & 7)) << 4);
    const int ck1 = (((4 + lg) ^ (lq & 7)) << 4);
    char* sPw = smem + 16384 + w * 1280;

    // one 32-key subtile: QK + exp + pack + z/PV accumulate (V from regs)
    auto do_subtile = [&](int jtc, const short8 vb[4]) {
        char* bK = smem + (jtc & 3) * 4096;
        const int j0c = jtc * 32;
        f32x4 sc[2];
#pragma unroll
        for (int ct = 0; ct < 2; ++ct) {
            const int rb = (ct * 16 + lq) * 128;
            f16x8 kb0 = *(const f16x8*)(bK + rb + ck0);
            f16x8 kb1 = *(const f16x8*)(bK + rb + ck1);
            f32x4 s = {0.f, 0.f, 0.f, 0.f};
            s = __builtin_amdgcn_mfma_f32_16x16x32_f16(kb0, qf0, s, 0, 0, 0);
            s = __builtin_amdgcn_mfma_f32_16x16x32_f16(kb1, qf1, s, 0, 0, 0);
            sc[ct] = s;
        }
        float p[2][4];
        if ((unsigned)(jtc - bt0) < 5u) {
#pragma unroll
            for (int s = 0; s < 5; ++s) {
                if (jtc == bt0 + s) {
#pragma unroll
                    for (int ct = 0; ct < 2; ++ct) {
                        f32x4 mtv = *(const f32x4*)&sMt[j0c + ct * 16 + lg * 4];
#pragma unroll
                        for (int reg = 0; reg < 4; ++reg)
                            p[ct][reg] = fexp2(sc[ct][reg] + mtv[reg] + ppos[s][ct][reg]);
                        band[s][ct][0] = cvtpk(p[ct][0], p[ct][1]);
                        band[s][ct][1] = cvtpk(p[ct][2], p[ct][3]);
                    }
                }
            }
        } else {
#pragma unroll
            for (int ct = 0; ct < 2; ++ct) {
                f32x4 mtv = *(const f32x4*)&sMt[j0c + ct * 16 + lg * 4];
#pragma unroll
                for (int reg = 0; reg < 4; ++reg)
                    p[ct][reg] = fexp2(sc[ct][reg] + mtv[reg]);
            }
        }
#pragma unroll
        for (int ct = 0; ct < 2; ++ct) {
            uint2v pw;
            pw[0] = cvtpk(p[ct][0], p[ct][1]);
            pw[1] = cvtpk(p[ct][2], p[ct][3]);
            *(uint2v*)(sPw + lq * 80 + ct * 32 + lg * 8) = pw;
        }
        short8 pa = *(const short8*)(sPw + lq * 80 + lg * 16);
        zacc = __builtin_amdgcn_mfma_f32_16x16x32_bf16(pa, ones, zacc, 0, 0, 0);
#pragma unroll
        for (int nt = 0; nt < 4; ++nt)
            acc[nt] = __builtin_amdgcn_mfma_f32_16x16x32_bf16(pa, vb[nt], acc[nt], 0, 0, 0);
    };

    // ---- main loop: 16 iters, 2 subtiles each, one barrier per iter ----
    for (int j = 0; j < 16; ++j) {
        if (j < 15) {   // stage K subtiles 2j+2,2j+3 + prefetch V frags to regs
            const int jn = 2 * j + 2;
            async_load16(smem + (jn & 3) * 4096 + t * 16,
                         Ksrc + (size_t)jn * 32 * HD);
            async_load16(smem + ((jn + 1) & 3) * 4096 + t * 16,
                         Ksrc + (size_t)(jn + 1) * 32 * HD);
#pragma unroll
            for (int nt = 0; nt < 4; ++nt) {
                nA[nt] = *(const short8*)(Vg + (size_t)nt * 16 * SEQ + jn * 32);
                nB[nt] = *(const short8*)(Vg + (size_t)nt * 16 * SEQ + jn * 32 + 32);
            }
        }

        do_subtile(2 * j, vA);
        do_subtile(2 * j + 1, vB);

        WAITV0();   // K DMAs + V reg loads all landed (had the whole iter)
        BAR();
#pragma unroll
        for (int nt = 0; nt < 4; ++nt) { vA[nt] = nA[nt]; vB[nt] = nB[nt]; }
    }

    // ---- epilogue: band-value term (overlay dead K ring + sPscr) ----
    char* bandLds = smem + w * 5120;
    {
        short8 z8 = {0, 0, 0, 0, 0, 0, 0, 0};
#pragma unroll
        for (int i = 0; i < 5; ++i)
            *(short8*)(bandLds + l * 16 + i * 1024) = z8;
    }
#pragma unroll
    for (int s = 0; s < 5; ++s) {
        const int jts = bt0 + s;
        if ((unsigned)jts < 32u) {
#pragma unroll
            for (int ct = 0; ct < 2; ++ct)
#pragma unroll
                for (int hh = 0; hh < 2; ++hh) {
                    const unsigned pw = band[s][ct][hh];
                    const int k0v  = jts * 32 + ct * 16 + lg * 4 + hh * 2;
                    const int rel0 = k0v - wrow0 - lq + 64;
                    if ((unsigned)rel0 < (unsigned)RK)
                        *(short*)(bandLds + lq * 320 + rel0 * 2) = (short)(pw & 0xffff);
                    if ((unsigned)(rel0 + 1) < (unsigned)RK)
                        *(short*)(bandLds + lq * 320 + rel0 * 2 + 2) = (short)(pw >> 16);
                }
        }
    }

    short8 bandA[5];
#pragma unroll
    for (int ks = 0; ks < 5; ++ks)
        bandA[ks] = *(const short8*)(bandLds + lq * 320 + ks * 64 + lg * 16);
#pragma unroll
    for (int nt = 0; nt < 4; ++nt) {
#pragma unroll
        for (int ks = 0; ks < 5; ++ks) {
            short8 eb = *(const short8*)&Evt[(size_t)(nt * 16 + lq) * 160 + ks * 32 + lg * 8];
            acc[nt] = __builtin_amdgcn_mfma_f32_16x16x32_bf16(bandA[ks], eb, acc[nt], 0, 0, 0);
        }
    }

#pragma unroll
    for (int nt = 0; nt < 4; ++nt) {
#pragma unroll
        for (int reg = 0; reg < 4; ++reg) {
            int qi = wrow0 + lg * 4 + reg;
            out[((size_t)b * SEQ + qi) * HDIM + h * HD + nt * 16 + lq] =
                acc[nt][reg] / zacc[reg];
        }
    }
}

extern "C" void kernel_launch(void* const* d_in, const int* in_sizes, int n_in,
                              void* d_out, int out_size, void* d_ws, size_t ws_size,
                              hipStream_t stream) {
    const float* X    = (const float*)d_in[0];
    const float* mask = (const float*)d_in[1];
    const float* Wq   = (const float*)d_in[2];
    const float* bq   = (const float*)d_in[3];
    const float* Wk   = (const float*)d_in[4];
    const float* bk   = (const float*)d_in[5];
    const float* Wv   = (const float*)d_in[6];
    const float* bv   = (const float*)d_in[7];
    const float* Ek   = (const float*)d_in[8];
    const float* Ev   = (const float*)d_in[9];
    float* out        = (float*)d_out;

    char* ws = (char*)d_ws;
    const size_t SZ_QKV = (size_t)BSZ * NH * SEQ * HD * 2;   // 6,291,456 B each
    const size_t SZ_W   = (size_t)HDIM * HDIM * 2;           // 1,179,648 B each
    _Float16* Qh  = (_Float16*)(ws);
    _Float16* Kh  = (_Float16*)(ws + SZ_QKV);
    short*    Vt  = (short*)   (ws + 2 * SZ_QKV);            // [bh][d][s] bf16
    _Float16* Xh  = (_Float16*)(ws + 3 * SZ_QKV);
    _Float16* Wtq = (_Float16*)(ws + 4 * SZ_QKV);
    _Float16* Wtk = (_Float16*)(ws + 4 * SZ_QKV + SZ_W);
    _Float16* Wtv = (_Float16*)(ws + 4 * SZ_QKV + 2 * SZ_W);
    _Float16* Ekh = (_Float16*)(ws + 4 * SZ_QKV + 3 * SZ_W);
    short*    Evt = (short*)   (ws + 4 * SZ_QKV + 3 * SZ_W + 20480);

    prep_kernel<<<NCONVB + NTRB, 256, 0, stream>>>(
        X, Ek, Ev, Wq, Wk, Wv, Xh, Ekh, Evt, Wtq, Wtk, Wtv);
    qkv_mfma_kernel<<<576, 256, 0, stream>>>(Xh, Wtq, Wtk, Wtv, bq, bk, bv, Qh, Kh, Vt);
    attn_mfma_kernel<<<768, 256, 0, stream>>>(Qh, Kh, Vt, mask, Ekh, Evt, out);
}

// Round 22
// 76.116 us; speedup vs baseline: 1.3748x; 1.3748x over previous
//
#include <hip/hip_runtime.h>
#include <hip/hip_bf16.h>
#include <math.h>

#define NH 12
#define SEQ 1024
#define HD 64
#define HDIM 768
#define BSZ 4
#define RK 129
#define FMIN -3.4028234663852886e38f
#define LOG2E 1.4426950408889634f

typedef __attribute__((ext_vector_type(8))) short short8;
typedef __attribute__((ext_vector_type(4))) short short4v;
typedef __attribute__((ext_vector_type(2))) unsigned uint2v;
typedef __attribute__((ext_vector_type(8))) _Float16 f16x8;
typedef __attribute__((ext_vector_type(4))) float f32x4;

__device__ inline short f2bf(float x) {
    union { __hip_bfloat16 h; short s; } u;
    u.h = __float2bfloat16(x);
    return u.s;
}
__device__ inline unsigned cvtpk(float lo, float hi) {
    unsigned r;
    asm("v_cvt_pk_bf16_f32 %0, %1, %2" : "=v"(r) : "v"(lo), "v"(hi));
    return r;
}
__device__ inline float fexp2(float x) {   // p = 2^x, single TRANS op
    float r;
    asm("v_exp_f32 %0, %1" : "=v"(r) : "v"(x));
    return r;
}

__device__ inline void async_load16(void* lds, const void* g) {
    __builtin_amdgcn_global_load_lds(
        (const __attribute__((address_space(1))) unsigned int*)g,
        (__attribute__((address_space(3))) unsigned int*)lds, 16, 0, 0);
}

#define BAR()    asm volatile("s_barrier" ::: "memory")
#define WAITV0() asm volatile("s_waitcnt vmcnt(0)" ::: "memory")
#define WAITV2() asm volatile("s_waitcnt vmcnt(2)" ::: "memory")

// ---------------- Kernel 0: prep = f16 convert (X, Ek) + Evt + W transpose --
#define NXCHUNK 393216   // 4096*768/8
#define NECHUNK 1032     // 129*64/8
#define NEVCHUNK 1280    // 64*160/8
#define NCONVB ((NXCHUNK + NECHUNK + NEVCHUNK + 255) / 256)   // 1548
#define NTRB   (144 * 3)                                      // 432
__global__ __launch_bounds__(256) void prep_kernel(
    const float* __restrict__ X, const float* __restrict__ Ek,
    const float* __restrict__ Ev,
    const float* __restrict__ Wq, const float* __restrict__ Wk, const float* __restrict__ Wv,
    _Float16* __restrict__ Xh, _Float16* __restrict__ Ekh, short* __restrict__ Evt,
    _Float16* __restrict__ Wtq, _Float16* __restrict__ Wtk, _Float16* __restrict__ Wtv)
{
    const int bidg = blockIdx.x;
    if (bidg < NCONVB) {
        int idx = bidg * 256 + threadIdx.x;
        if (idx < NXCHUNK + NECHUNK) {
            const float* src;
            _Float16* dst;
            if (idx < NXCHUNK) { src = X; dst = Xh; }
            else { idx -= NXCHUNK; src = Ek; dst = Ekh; }
            float4 a = ((const float4*)src)[idx * 2];
            float4 b = ((const float4*)src)[idx * 2 + 1];
            f16x8 o;
            o[0] = (_Float16)a.x; o[1] = (_Float16)a.y; o[2] = (_Float16)a.z; o[3] = (_Float16)a.w;
            o[4] = (_Float16)b.x; o[5] = (_Float16)b.y; o[6] = (_Float16)b.z; o[7] = (_Float16)b.w;
            ((f16x8*)dst)[idx] = o;
        } else if (idx < NXCHUNK + NECHUNK + NEVCHUNK) {
            idx -= NXCHUNK + NECHUNK;
            const int dim = idx / 20;
            const int r0  = (idx % 20) * 8;
            short8 o;
#pragma unroll
            for (int e = 0; e < 8; ++e) {
                int rel = r0 + e;
                float v = (rel < RK) ? Ev[(size_t)rel * HD + dim] : 0.0f;
                o[e] = f2bf(v);
            }
            *(short8*)&Evt[(size_t)dim * 160 + r0] = o;
        }
        return;
    }
    const int bid2 = bidg - NCONVB;
    const int z = bid2 / 144;
    const int r = bid2 % 144;
    const float* __restrict__ W = (z == 0) ? Wq : (z == 1) ? Wk : Wv;
    _Float16* __restrict__ Wt   = (z == 0) ? Wtq : (z == 1) ? Wtk : Wtv;

    __shared__ float sT[64][65];
    const int t  = threadIdx.x;
    const int k0 = (r / 12) * 64;
    const int n0 = (r % 12) * 64;

    const int c  = (t & 15) * 4;
    const int kr = t >> 4;
#pragma unroll
    for (int rr = 0; rr < 4; ++rr) {
        float4 v = *(const float4*)&W[(size_t)(k0 + kr + rr * 16) * HDIM + n0 + c];
        sT[c + 0][kr + rr * 16] = v.x;
        sT[c + 1][kr + rr * 16] = v.y;
        sT[c + 2][kr + rr * 16] = v.z;
        sT[c + 3][kr + rr * 16] = v.w;
    }
    __syncthreads();
    const int rn = t >> 2;
    const int ck = (t & 3) * 16;
#pragma unroll
    for (int g = 0; g < 2; ++g) {
        f16x8 o;
#pragma unroll
        for (int e = 0; e < 8; ++e) o[e] = (_Float16)sT[rn][ck + g * 8 + e];
        *(f16x8*)&Wt[(size_t)(n0 + rn) * HDIM + k0 + ck + g * 8] = o;
    }
}

// ---------------- Kernel 1: QKV projection via f16 MFMA (R8 shape) ---------
// Q is scaled by log2(e) at store so attn can use exp2 directly.
__global__ __launch_bounds__(256) void qkv_mfma_kernel(
    const _Float16* __restrict__ Xh,
    const _Float16* __restrict__ Wtq, const _Float16* __restrict__ Wtk, const _Float16* __restrict__ Wtv,
    const float* __restrict__ bq, const float* __restrict__ bk, const float* __restrict__ bv,
    _Float16* __restrict__ Qo, _Float16* __restrict__ Ko, short* __restrict__ Vt)
{
    int bid = blockIdx.x;
    bid = (bid & 7) * 72 + (bid >> 3);          // XCD swizzle (576 = 8*72)
    const int which = bid / 192;
    const int rem   = bid % 192;
    const int n0    = (rem / 32) * 128;
    const int m0    = (rem % 32) * 128;
    const _Float16* __restrict__ Wt = (which == 0) ? Wtq : (which == 1) ? Wtk : Wtv;
    const float* __restrict__ bias  = (which == 0) ? bq : (which == 1) ? bk : bv;
    const float qscale = (which == 0) ? LOG2E : 1.0f;

    __shared__ __align__(16) _Float16 sA[128 * 64];
    __shared__ __align__(16) _Float16 sB[128 * 64];

    const int t  = threadIdx.x;
    const int w  = t >> 6, l = t & 63;
    const int lq = l & 15, lg = l >> 4;
    const int wr = w >> 1, wc = w & 1;

    f32x4 acc[4][4];
#pragma unroll
    for (int i = 0; i < 4; ++i)
#pragma unroll
        for (int j = 0; j < 4; ++j) acc[i][j] = (f32x4){0.f, 0.f, 0.f, 0.f};

    for (int k0 = 0; k0 < HDIM; k0 += 64) {
        __syncthreads();
#pragma unroll
        for (int r = 0; r < 4; ++r) {
            const int cib = r * 256 + w * 64;
            const int ci  = cib + l;
            const int row = ci >> 3, cr = ci & 7;
            const int lc  = cr ^ (row & 7);
            async_load16(&sA[(size_t)cib * 8],
                         &Xh[(size_t)(m0 + row) * HDIM + k0 + lc * 8]);
            async_load16(&sB[(size_t)cib * 8],
                         &Wt[(size_t)(n0 + row) * HDIM + k0 + lc * 8]);
        }
        __syncthreads();

        f16x8 af[4][2], bf[4][2];
#pragma unroll
        for (int i = 0; i < 4; ++i) {
#pragma unroll
            for (int ks = 0; ks < 2; ++ks) {
                int ra = wr * 64 + i * 16 + lq;
                af[i][ks] = *(const f16x8*)((const char*)sA +
                            ra * 128 + ((ks * 64 + lg * 16) ^ ((ra & 7) << 4)));
                int rb = wc * 64 + i * 16 + lq;
                bf[i][ks] = *(const f16x8*)((const char*)sB +
                            rb * 128 + ((ks * 64 + lg * 16) ^ ((rb & 7) << 4)));
            }
        }
#pragma unroll
        for (int i = 0; i < 4; ++i)
#pragma unroll
            for (int j = 0; j < 4; ++j) {
                acc[i][j] = __builtin_amdgcn_mfma_f32_16x16x32_f16(af[i][0], bf[j][0], acc[i][j], 0, 0, 0);
                acc[i][j] = __builtin_amdgcn_mfma_f32_16x16x32_f16(af[i][1], bf[j][1], acc[i][j], 0, 0, 0);
            }
    }

    _Float16* __restrict__ Yh = (which == 0) ? Qo : Ko;
#pragma unroll
    for (int i = 0; i < 4; ++i) {
        const int mb = m0 + wr * 64 + i * 16 + lg * 4;
        const int bb = mb >> 10, ss = mb & 1023;
#pragma unroll
        for (int j = 0; j < 4; ++j) {
            const int n  = n0 + wc * 64 + j * 16 + lq;
            const float bv4 = bias[n];
            const int hh = n >> 6, dd = n & 63;
            if (which == 2) {
                short4v pk;
#pragma unroll
                for (int reg = 0; reg < 4; ++reg)
                    pk[reg] = f2bf(acc[i][j][reg] + bv4);
                *(short4v*)&Vt[((size_t)(bb * NH + hh) * HD + dd) * SEQ + ss] = pk;
            } else {
#pragma unroll
                for (int reg = 0; reg < 4; ++reg) {
                    const size_t off = ((size_t)(bb * NH + hh) * SEQ + ss + reg) * HD + dd;
                    Yh[off] = (_Float16)((acc[i][j][reg] + bv4) * qscale);
                }
            }
        }
    }
}

// ---------------- Kernel 2: 32-key TRIPLE-buffered attention (R16) ---------
// Scalar band branching (readfirstlane) + exp2 path (Q pre-scaled). No LDS
// overlays: every region single-owner for the kernel lifetime.
__global__ __launch_bounds__(256, 3) void attn_mfma_kernel(
    const _Float16* __restrict__ Q, const _Float16* __restrict__ K,
    const short* __restrict__ Vt, const float* __restrict__ mask,
    const _Float16* __restrict__ Ekh, const short* __restrict__ Evt,
    float* __restrict__ out)
{
    __shared__ __align__(16) char smem[50688];
    // [0)      sK   [3][32][64] f16   (12288 B)
    // [12288)  sVT  [3][64][32] bf16  (12288 B)
    // [24576)  sPscr[4][16][40] bf16  (5120 B, stride 80B)
    // [29696)  sPpos[4][16][132] f16  (16896 B)
    // [46592)  sMt  [1024] f32        (4096 B)
    _Float16* sPpos = (_Float16*)(smem + 29696);
    float*    sMt   = (float*)(smem + 46592);

    int bid = blockIdx.x;
    bid = (bid & 7) * 96 + (bid >> 3);   // XCD chunk: 768 = 8*96
    const int bh = bid >> 4;             // 0..47
    const int i0 = (bid & 15) * 64;
    const int b  = bh / NH;
    const int h  = bh - b * NH;

    const int t  = threadIdx.x;
    const int w  = t >> 6;
    const int l  = t & 63;
    const int lq = l & 15;
    const int lg = l >> 4;
    const int wrow0 = i0 + w * 16;
    const int bt0 = __builtin_amdgcn_readfirstlane(((wrow0 - 64 + 1024) >> 5) - 32);

    const int krow = t >> 3, klc = (t & 7) ^ (krow & 7);
    const int vrow = t >> 2, vlc = (t & 3) ^ ((vrow >> 1) & 3);   // row bits 1-2
    const _Float16* Ksrc = K + ((size_t)bh * SEQ + krow) * HD + klc * 8;
    const short*    Vsrc = Vt + ((size_t)bh * HD + vrow) * SEQ + vlc * 8;

    // ---- stage tiles 0,1 into buffers 0,1 ----
    async_load16(smem + t * 16,          Ksrc);
    async_load16(smem + 12288 + t * 16,  Vsrc);
    async_load16(smem + 4096 + t * 16,   Ksrc + 32 * HD);
    async_load16(smem + 16384 + t * 16,  Vsrc + 32);

    const _Float16* qp = Q + ((size_t)bh * SEQ + wrow0 + lq) * HD;
    f16x8 qf0 = *(const f16x8*)&qp[lg * 8];
    f16x8 qf1 = *(const f16x8*)&qp[32 + lg * 8];

    // P_pos = Q' @ E_key^T (exp2 domain; Q' = log2e*Q), stored [q=row][rel]
#pragma unroll
    for (int nt = 0; nt < 9; ++nt) {
        int cc = nt * 16 + lq;
        f16x8 eb0 = {0, 0, 0, 0, 0, 0, 0, 0};
        f16x8 eb1 = {0, 0, 0, 0, 0, 0, 0, 0};
        if (cc < RK) {
            eb0 = *(const f16x8*)&Ekh[(size_t)cc * HD + lg * 8];
            eb1 = *(const f16x8*)&Ekh[(size_t)cc * HD + 32 + lg * 8];
        }
        f32x4 pc = {0.f, 0.f, 0.f, 0.f};
        pc = __builtin_amdgcn_mfma_f32_16x16x32_f16(qf0, eb0, pc, 0, 0, 0);
        pc = __builtin_amdgcn_mfma_f32_16x16x32_f16(qf1, eb1, pc, 0, 0, 0);
        if (cc < RK) {
#pragma unroll
            for (int reg = 0; reg < 4; ++reg)
                sPpos[(w * 16 + lg * 4 + reg) * 132 + cc] = (_Float16)pc[reg];
        }
    }

    // mask -> LDS as f32 additive exp2-domain terms: mt = ((1-m)*FMIN)*log2e
    {
        float4 mv = *(const float4*)&mask[(size_t)b * SEQ + t * 4];
        float4 mo;
        mo.x = ((1.0f - mv.x) * FMIN) * LOG2E;
        mo.y = ((1.0f - mv.y) * FMIN) * LOG2E;
        mo.z = ((1.0f - mv.z) * FMIN) * LOG2E;
        mo.w = ((1.0f - mv.w) * FMIN) * LOG2E;
        *(float4*)&sMt[t * 4] = mo;
    }

    asm volatile("s_waitcnt vmcnt(2) lgkmcnt(0)" ::: "memory");  // tile0 done
    BAR();

    f32x4 acc[4];
#pragma unroll
    for (int nt = 0; nt < 4; ++nt) acc[nt] = (f32x4){0.f, 0.f, 0.f, 0.f};
    f32x4 zacc = {0.f, 0.f, 0.f, 0.f};

    const short8 ones = {0x3F80, 0x3F80, 0x3F80, 0x3F80,
                         0x3F80, 0x3F80, 0x3F80, 0x3F80};  // bf16 1.0 x8

    unsigned band[5][2][2];
#pragma unroll
    for (int s = 0; s < 5; ++s)
#pragma unroll
        for (int ct = 0; ct < 2; ++ct) { band[s][ct][0] = 0u; band[s][ct][1] = 0u; }

    const int ck0 = ((lg ^ (lq & 7)) << 4);
    const int ck1 = (((4 + lg) ^ (lq & 7)) << 4);
    char* sPw = smem + 24576 + w * 1280;
    const int vslot = (lg ^ ((lq >> 1) & 3)) << 4;   // sVT read slot

    char* bK0 = smem;          char* bK1 = smem + 4096;  char* bK2 = smem + 8192;
    char* bV0 = smem + 12288;  char* bV1 = smem + 16384; char* bV2 = smem + 20480;

    // ---- main loop: 32 tiles of 32 keys ----
    for (int jt = 0; jt < 32; ++jt) {
        const int j0 = jt * 32;

        if (jt < 30) {   // stage tile jt+2 into the 3rd buffer
            const int jn0 = j0 + 64;
            async_load16(bK2 + t * 16, Ksrc + (size_t)jn0 * HD);
            async_load16(bV2 + t * 16, Vsrc + jn0);
        }

        // swapped QK^T: sc[ct][reg] = S'[k=j0+16ct+4lg+reg][q=lq] (exp2 dom.)
        f32x4 sc[2];
#pragma unroll
        for (int ct = 0; ct < 2; ++ct) {
            const int rb = (ct * 16 + lq) * 128;
            f16x8 kb0 = *(const f16x8*)(bK0 + rb + ck0);
            f16x8 kb1 = *(const f16x8*)(bK0 + rb + ck1);
            f32x4 s = {0.f, 0.f, 0.f, 0.f};
            s = __builtin_amdgcn_mfma_f32_16x16x32_f16(kb0, qf0, s, 0, 0, 0);
            s = __builtin_amdgcn_mfma_f32_16x16x32_f16(kb1, qf1, s, 0, 0, 0);
            sc[ct] = s;
        }

        // p = exp2(s' + mt')  (scalar-branched band handling)
        float p[2][4];
        if ((unsigned)(jt - bt0) < 5u) {
#pragma unroll
            for (int s = 0; s < 5; ++s) {
                if (jt == bt0 + s) {
#pragma unroll
                    for (int ct = 0; ct < 2; ++ct) {
                        const int kbase = j0 + ct * 16 + lg * 4;
                        const int relb  = kbase - wrow0 - lq + 64;
                        f32x4 mtv = *(const f32x4*)&sMt[kbase];
#pragma unroll
                        for (int reg = 0; reg < 4; ++reg) {
                            float sv = sc[ct][reg] + mtv[reg];
                            const int rel = relb + reg;
                            const bool inb = ((unsigned)rel < (unsigned)RK);
                            if (inb) sv += (float)sPpos[(w * 16 + lq) * 132 + rel];
                            p[ct][reg] = fexp2(sv);
                        }
                        band[s][ct][0] = cvtpk(p[ct][0], p[ct][1]);
                        band[s][ct][1] = cvtpk(p[ct][2], p[ct][3]);
                    }
                }
            }
        } else {
#pragma unroll
            for (int ct = 0; ct < 2; ++ct) {
                f32x4 mtv = *(const f32x4*)&sMt[j0 + ct * 16 + lg * 4];
#pragma unroll
                for (int reg = 0; reg < 4; ++reg)
                    p[ct][reg] = fexp2(sc[ct][reg] + mtv[reg]);
            }
        }

        // pack P -> sPscr[q=lq][k] (b64 writes, 80B row stride, no XOR)
#pragma unroll
        for (int ct = 0; ct < 2; ++ct) {
            uint2v pw;
            pw[0] = cvtpk(p[ct][0], p[ct][1]);
            pw[1] = cvtpk(p[ct][2], p[ct][3]);
            *(uint2v*)(sPw + lq * 80 + ct * 32 + lg * 8) = pw;
        }

        short8 pa = *(const short8*)(sPw + lq * 80 + lg * 16);
        zacc = __builtin_amdgcn_mfma_f32_16x16x32_bf16(pa, ones, zacc, 0, 0, 0);

#pragma unroll
        for (int nt = 0; nt < 4; ++nt) {
            short8 vb = *(const short8*)(bV0 + (nt * 16 + lq) * 64 + vslot);
            acc[nt] = __builtin_amdgcn_mfma_f32_16x16x32_bf16(pa, vb, acc[nt], 0, 0, 0);
        }

        if (jt < 30)       WAITV2();   // tile jt+1 landed; jt+2 still flying
        else if (jt == 30) WAITV0();   // tile 31 landed
        BAR();

        char* tk = bK0; bK0 = bK1; bK1 = bK2; bK2 = tk;
        char* tv = bV0; bV0 = bV1; bV1 = bV2; bV2 = tv;
    }

    // ---- epilogue: band-value term ----
    char* bandLds = smem + w * 5120;
    {
        short8 z8 = {0, 0, 0, 0, 0, 0, 0, 0};
#pragma unroll
        for (int i = 0; i < 5; ++i)
            *(short8*)(bandLds + l * 16 + i * 1024) = z8;
    }
#pragma unroll
    for (int s = 0; s < 5; ++s) {
        const int jts = bt0 + s;
        if ((unsigned)jts < 32u) {
#pragma unroll
            for (int ct = 0; ct < 2; ++ct)
#pragma unroll
                for (int hh = 0; hh < 2; ++hh) {
                    const unsigned pw = band[s][ct][hh];
                    const int k0v  = jts * 32 + ct * 16 + lg * 4 + hh * 2;
                    const int rel0 = k0v - wrow0 - lq + 64;
                    if ((unsigned)rel0 < (unsigned)RK)
                        *(short*)(bandLds + lq * 320 + rel0 * 2) = (short)(pw & 0xffff);
                    if ((unsigned)(rel0 + 1) < (unsigned)RK)
                        *(short*)(bandLds + lq * 320 + rel0 * 2 + 2) = (short)(pw >> 16);
                }
        }
    }

    short8 bandA[5];
#pragma unroll
    for (int ks = 0; ks < 5; ++ks)
        bandA[ks] = *(const short8*)(bandLds + lq * 320 + ks * 64 + lg * 16);
#pragma unroll
    for (int nt = 0; nt < 4; ++nt) {
#pragma unroll
        for (int ks = 0; ks < 5; ++ks) {
            short8 eb = *(const short8*)&Evt[(size_t)(nt * 16 + lq) * 160 + ks * 32 + lg * 8];
            acc[nt] = __builtin_amdgcn_mfma_f32_16x16x32_bf16(bandA[ks], eb, acc[nt], 0, 0, 0);
        }
    }

#pragma unroll
    for (int nt = 0; nt < 4; ++nt) {
#pragma unroll
        for (int reg = 0; reg < 4; ++reg) {
            int qi = wrow0 + lg * 4 + reg;
            out[((size_t)b * SEQ + qi) * HDIM + h * HD + nt * 16 + lq] =
                acc[nt][reg] / zacc[reg];
        }
    }
}

extern "C" void kernel_launch(void* const* d_in, const int* in_sizes, int n_in,
                              void* d_out, int out_size, void* d_ws, size_t ws_size,
                              hipStream_t stream) {
    const float* X    = (const float*)d_in[0];
    const float* mask = (const float*)d_in[1];
    const float* Wq   = (const float*)d_in[2];
    const float* bq   = (const float*)d_in[3];
    const float* Wk   = (const float*)d_in[4];
    const float* bk   = (const float*)d_in[5];
    const float* Wv   = (const float*)d_in[6];
    const float* bv   = (const float*)d_in[7];
    const float* Ek   = (const float*)d_in[8];
    const float* Ev   = (const float*)d_in[9];
    float* out        = (float*)d_out;

    char* ws = (char*)d_ws;
    const size_t SZ_QKV = (size_t)BSZ * NH * SEQ * HD * 2;   // 6,291,456 B each
    const size_t SZ_W   = (size_t)HDIM * HDIM * 2;           // 1,179,648 B each
    _Float16* Qh  = (_Float16*)(ws);
    _Float16* Kh  = (_Float16*)(ws + SZ_QKV);
    short*    Vt  = (short*)   (ws + 2 * SZ_QKV);            // [bh][d][s] bf16
    _Float16* Xh  = (_Float16*)(ws + 3 * SZ_QKV);
    _Float16* Wtq = (_Float16*)(ws + 4 * SZ_QKV);
    _Float16* Wtk = (_Float16*)(ws + 4 * SZ_QKV + SZ_W);
    _Float16* Wtv = (_Float16*)(ws + 4 * SZ_QKV + 2 * SZ_W);
    _Float16* Ekh = (_Float16*)(ws + 4 * SZ_QKV + 3 * SZ_W);
    short*    Evt = (short*)   (ws + 4 * SZ_QKV + 3 * SZ_W + 20480);

    prep_kernel<<<NCONVB + NTRB, 256, 0, stream>>>(
        X, Ek, Ev, Wq, Wk, Wv, Xh, Ekh, Evt, Wtq, Wtk, Wtv);
    qkv_mfma_kernel<<<576, 256, 0, stream>>>(Xh, Wtq, Wtk, Wtv, bq, bk, bv, Qh, Kh, Vt);
    attn_mfma_kernel<<<768, 256, 0, stream>>>(Qh, Kh, Vt, mask, Ekh, Evt, out);
}